// Round 5
// baseline (679.256 us; speedup 1.0000x reference)
//
#include <hip/hip_runtime.h>
#include <stdint.h>

// ---------------------------------------------------------------------------
// QuantQwenMLP: W4A8 fake-quant SwiGLU MLP.
//   B=4 S=2048 H=2048 I=5632  -> M = B*S = 8192 tokens
// R6 -> R7: every structure so far capped ~33% MfmaUtil at its single-pipe
// bandwidth ceiling (flat 64x64: TCP demand 96 B/MFMA-cyc vs ~32/SIMD supply
// = 33% cap, measured 33.5; full-LDS: ds_read pipe cap ~33%, measured 32.4).
// Hybrid splits traffic across BOTH pipes: A staged in LDS (1/3 of bytes,
// shared operand), B flat from L1 (TCP demand 96->64 => cap 50%), 64x64/wave
// keeps 2 waves/SIMD. Staging is reg-staged (T14 load-early/write-late) so
// ALL vmcnt is compiler-managed; sync = lgkmcnt(0) + raw s_barrier once per
// 4 k-steps (no __syncthreads vmcnt(0) drain, no hand-counted vmcnt races).
// Single GEMM mirrored (stage Wd, flat A; flat-only cap was 25%).
//
// Flat layout for int8 matrix [R][C] (C % 32 == 0), 16-B chunks:
//   chunk(r, c16) -> byte ((r>>5)*(C>>5) + (c16>>1))*1024
//                    + (((c16&1)<<5) | (r&31))*16
// A wave's fragment (row-group g, k-step ks) is the contiguous 1024-B block
//   ((g*(C>>5)+ks)<<10) + lane*16.
// ---------------------------------------------------------------------------

typedef int i32x4  __attribute__((ext_vector_type(4)));
typedef int i32x16 __attribute__((ext_vector_type(16)));

#define MFMA_I8 __builtin_amdgcn_mfma_i32_32x32x32_i8
#define LDF(p, o) (*(const i32x4*)((p) + (o)))
#define LGKM0() asm volatile("s_waitcnt lgkmcnt(0)" ::: "memory")
#define SCHEDB() __builtin_amdgcn_sched_barrier(0)
#define BAR()   __builtin_amdgcn_s_barrier()

__device__ __forceinline__ int pack4(float4 v, float scale, float qmax) {
    int a = (int)fminf(fmaxf(rintf(v.x / scale), -qmax), qmax);
    int b = (int)fminf(fmaxf(rintf(v.y / scale), -qmax), qmax);
    int c = (int)fminf(fmaxf(rintf(v.z / scale), -qmax), qmax);
    int d = (int)fminf(fmaxf(rintf(v.w / scale), -qmax), qmax);
    return (a & 255) | ((b & 255) << 8) | ((c & 255) << 16) | (d << 24);
}

// ---------------------------------------------------------------------------
// Per-row symmetric fake-quant writing the flat fragment-major layout.
// ---------------------------------------------------------------------------
__global__ __launch_bounds__(256) void quant_rows_shuf(
    const float* __restrict__ src, int8_t* __restrict__ dst,
    float* __restrict__ scales, int C4, float qmax)
{
    __shared__ float4 buf[1408];        // up to 5632 floats = 22.5 KB
    __shared__ float wmax[4];
    const int r = blockIdx.x;
    const float4* s4 = (const float4*)src + (long)r * C4;

    float am = 0.f;
    for (int i = threadIdx.x; i < C4; i += 256) {
        float4 v = s4[i];
        buf[i] = v;
        am = fmaxf(am, fmaxf(fmaxf(fabsf(v.x), fabsf(v.y)),
                             fmaxf(fabsf(v.z), fabsf(v.w))));
    }
    #pragma unroll
    for (int off = 32; off; off >>= 1)
        am = fmaxf(am, __shfl_xor(am, off));
    if ((threadIdx.x & 63) == 0) wmax[threadIdx.x >> 6] = am;
    __syncthreads();
    const float amax = fmaxf(fmaxf(wmax[0], wmax[1]), fmaxf(wmax[2], wmax[3]));
    const float scale = fmaxf(amax / qmax, 1e-8f);
    if (threadIdx.x == 0) scales[r] = scale;

    const int C16 = C4 >> 2;            // 16-B chunks per row
    const int KC  = C4 >> 3;            // 32-B k-steps per row (C>>5)
    const int g   = r >> 5;
    const int rl  = r & 31;
    for (int i = threadIdx.x; i < C16; i += 256) {
        float4 v0 = buf[4*i+0], v1 = buf[4*i+1];
        float4 v2 = buf[4*i+2], v3 = buf[4*i+3];
        i32x4 q;
        q[0] = pack4(v0, scale, qmax);
        q[1] = pack4(v1, scale, qmax);
        q[2] = pack4(v2, scale, qmax);
        q[3] = pack4(v3, scale, qmax);
        size_t off = ((size_t)(g * KC + (i >> 1)) << 10)
                   + ((size_t)((((i & 1) << 5) | rl)) << 4);
        *(i32x4*)(dst + off) = q;
    }
}

// ---------------------------------------------------------------------------
// Fused gate+up int8 GEMM with SwiGLU epilogue (fp32 H out).
// Block 128(M)x128(N), 4 waves, wave tile 64x64. A staged in LDS (2 buf x
// 16 KB, tile = 4 rowgroups x 4 ksteps x 1024 B); G/U flat from L1 with
// in-place rolling prefetch (parity f/h). 8 MFMA + 4 B-loads + 2 A-ds_reads
// per k-step; 1 barrier per 4 k-steps.
// ---------------------------------------------------------------------------
__global__ __launch_bounds__(256, 2) void gemm_dual_hyb(
    const int8_t* __restrict__ Ash, const float* __restrict__ sA,
    const int8_t* __restrict__ Gsh, const float* __restrict__ sBg,
    const int8_t* __restrict__ Ush, const float* __restrict__ sBu,
    float* __restrict__ H, int M, int N, int K)
{
    __shared__ int8_t Asm[2 * 16384];

    const int KC   = K >> 5;            // 64 for K=2048
    const int tid  = threadIdx.x;
    const int lane = tid & 63;
    const int cl   = lane & 31;
    const int kq   = lane >> 5;
    const int wave = tid >> 6;
    const int wm   = (wave >> 1) * 64;
    const int wn   = (wave & 1) * 64;

    // column-band XCD swizzle
    int bx, by;
    {
        const int nwg = gridDim.x * gridDim.y;
        int w = blockIdx.y * gridDim.x + blockIdx.x;
        int t = ((nwg & 7) == 0) ? ((w & 7) * (nwg >> 3) + (w >> 3)) : w;
        bx = t / gridDim.y;
        by = t - bx * gridDim.y;
    }
    const long m0 = (long)by * 128;
    const long n0 = (long)bx * 128;

    const size_t KB = (size_t)KC << 10;     // bytes per 32-row group
    // stage source: wave w stages block rowgroup w (4 chunks of 1024 B)
    const int8_t* ps = Ash + (size_t)((m0 >> 5) + wave) * KB + lane * 16;
    // flat B streams
    const int8_t* pg0 = Gsh + (size_t)((n0 + wn) >> 5) * KB + lane * 16;
    const int8_t* pg1 = pg0 + KB;
    const int8_t* pu0 = Ush + (size_t)((n0 + wn) >> 5) * KB + lane * 16;
    const int8_t* pu1 = pu0 + KB;

    const int aoff = (wave >> 1) * 8192 + lane * 16;   // wave's A rowgroup pair
    const int woff = wave * 4096 + lane * 16;          // stage dst in tile

    i32x16 accg[2][2], accu[2][2];
    #pragma unroll
    for (int i = 0; i < 2; ++i)
        #pragma unroll
        for (int j = 0; j < 2; ++j) {
            accg[i][j] = i32x16{0,0,0,0,0,0,0,0,0,0,0,0,0,0,0,0};
            accu[i][j] = i32x16{0,0,0,0,0,0,0,0,0,0,0,0,0,0,0,0};
        }

#define DUAL_MFMA(A0, A1, G0, G1, U0, U1) do { \
    __builtin_amdgcn_s_setprio(1); \
    accg[0][0] = MFMA_I8(A0, G0, accg[0][0], 0, 0, 0); \
    accg[0][1] = MFMA_I8(A0, G1, accg[0][1], 0, 0, 0); \
    accg[1][0] = MFMA_I8(A1, G0, accg[1][0], 0, 0, 0); \
    accg[1][1] = MFMA_I8(A1, G1, accg[1][1], 0, 0, 0); \
    accu[0][0] = MFMA_I8(A0, U0, accu[0][0], 0, 0, 0); \
    accu[0][1] = MFMA_I8(A0, U1, accu[0][1], 0, 0, 0); \
    accu[1][0] = MFMA_I8(A1, U0, accu[1][0], 0, 0, 0); \
    accu[1][1] = MFMA_I8(A1, U1, accu[1][1], 0, 0, 0); \
    __builtin_amdgcn_s_setprio(0); } while (0)

    // ---- prologue: stage tile 0 (reg-staged), preload B ksteps 0/1 ----
    {
        i32x4 s0 = LDF(ps, 0), s1 = LDF(ps, 1024);
        i32x4 s2 = LDF(ps, 2048), s3 = LDF(ps, 3072);
        *(i32x4*)(Asm + woff +    0) = s0;
        *(i32x4*)(Asm + woff + 1024) = s1;
        *(i32x4*)(Asm + woff + 2048) = s2;
        *(i32x4*)(Asm + woff + 3072) = s3;
    }
    ps += 4096;
    i32x4 fg0 = LDF(pg0, 0),    fg1 = LDF(pg1, 0);
    i32x4 fu0 = LDF(pu0, 0),    fu1 = LDF(pu1, 0);
    i32x4 hg0 = LDF(pg0, 1024), hg1 = LDF(pg1, 1024);
    i32x4 hu0 = LDF(pu0, 1024), hu1 = LDF(pu1, 1024);
    LGKM0(); SCHEDB(); BAR();

    const int NT = KC >> 2;             // 16 tiles of 4 k-steps
    for (int kt = 0; kt < NT; ++kt) {
        const int8_t* cb = Asm + (kt & 1) * 16384;
        int8_t* nb = Asm + ((kt + 1) & 1) * 16384;
        const bool pf = (kt + 1) < NT;

        // issue next tile's stage loads early (landing hidden under 32 MFMA)
        i32x4 st0, st1, st2, st3;
        if (pf) {
            st0 = LDF(ps, 0);    st1 = LDF(ps, 1024);
            st2 = LDF(ps, 2048); st3 = LDF(ps, 3072);
        }
        ps += 4096;

        // A fragments ks0/ks1
        i32x4 aA0 = *(const i32x4*)(cb + aoff +    0);
        i32x4 aB0 = *(const i32x4*)(cb + aoff + 4096);
        i32x4 aA1 = *(const i32x4*)(cb + aoff + 1024);
        i32x4 aB1 = *(const i32x4*)(cb + aoff + 5120);

        DUAL_MFMA(aA0, aB0, fg0, fg1, fu0, fu1);
        fg0 = LDF(pg0, 2048); fg1 = LDF(pg1, 2048);
        fu0 = LDF(pu0, 2048); fu1 = LDF(pu1, 2048);

        // A fragments ks2/ks3 (issued before ks1 MFMAs for ds latency)
        i32x4 aA2 = *(const i32x4*)(cb + aoff + 2048);
        i32x4 aB2 = *(const i32x4*)(cb + aoff + 6144);
        i32x4 aA3 = *(const i32x4*)(cb + aoff + 3072);
        i32x4 aB3 = *(const i32x4*)(cb + aoff + 7168);

        DUAL_MFMA(aA1, aB1, hg0, hg1, hu0, hu1);
        hg0 = LDF(pg0, 3072); hg1 = LDF(pg1, 3072);
        hu0 = LDF(pu0, 3072); hu1 = LDF(pu1, 3072);
        pg0 += 2048; pg1 += 2048; pu0 += 2048; pu1 += 2048;

        DUAL_MFMA(aA2, aB2, fg0, fg1, fu0, fu1);
        fg0 = LDF(pg0, 2048); fg1 = LDF(pg1, 2048);
        fu0 = LDF(pu0, 2048); fu1 = LDF(pu1, 2048);

        DUAL_MFMA(aA3, aB3, hg0, hg1, hu0, hu1);
        hg0 = LDF(pg0, 3072); hg1 = LDF(pg1, 3072);
        hu0 = LDF(pu0, 3072); hu1 = LDF(pu1, 3072);
        pg0 += 2048; pg1 += 2048; pu0 += 2048; pu1 += 2048;

        // write-late: stage lands just before the barrier
        if (pf) {
            *(i32x4*)(nb + woff +    0) = st0;
            *(i32x4*)(nb + woff + 1024) = st1;
            *(i32x4*)(nb + woff + 2048) = st2;
            *(i32x4*)(nb + woff + 3072) = st3;
        }
        LGKM0(); SCHEDB(); BAR();
    }

    // Epilogue. 32x32 C/D layout: col = lane&31, row = (reg&3)+8*(reg>>2)+4*(lane>>5).
    float sg[2], su[2];
    #pragma unroll
    for (int ni = 0; ni < 2; ++ni) {
        long n = n0 + wn + ni * 32 + cl;
        sg[ni] = sBg[n];
        su[ni] = sBu[n];
    }
    #pragma unroll
    for (int mi = 0; mi < 2; ++mi) {
        #pragma unroll
        for (int reg = 0; reg < 16; ++reg) {
            long m = m0 + wm + mi * 32 + (reg & 3) + 8 * (reg >> 2) + 4 * kq;
            float sa = sA[m];
            #pragma unroll
            for (int ni = 0; ni < 2; ++ni) {
                long n = n0 + wn + ni * 32 + cl;
                float g = (float)accg[mi][ni][reg] * sa * sg[ni];
                float u = (float)accu[mi][ni][reg] * sa * su[ni];
                float s = 1.f / (1.f + expf(-g));
                H[m * N + n] = (g * s) * u;
            }
        }
    }
}

// ---------------------------------------------------------------------------
// Single int8 GEMM, hybrid: B (Wd) staged in LDS, A flat from L1.
// Block 256(M)x128(N), 4 waves, wave tile 128x64. 8 MFMA + 4 A-loads +
// 2 B-ds_reads per k-step.
// ---------------------------------------------------------------------------
__global__ __launch_bounds__(256, 2) void gemm_single_hyb(
    const int8_t* __restrict__ Ash, const float* __restrict__ sA,
    const int8_t* __restrict__ Bsh, const float* __restrict__ sB,
    float* __restrict__ O, int M, int N, int K)
{
    __shared__ int8_t Bsm[2 * 16384];

    const int KC   = K >> 5;            // 176 for K=5632
    const int tid  = threadIdx.x;
    const int lane = tid & 63;
    const int cl   = lane & 31;
    const int kq   = lane >> 5;
    const int wave = tid >> 6;
    const int wm   = (wave >> 1) * 128;
    const int wn   = (wave & 1) * 64;

    int bx, by;
    {
        const int nwg = gridDim.x * gridDim.y;
        int w = blockIdx.y * gridDim.x + blockIdx.x;
        int t = ((nwg & 7) == 0) ? ((w & 7) * (nwg >> 3) + (w >> 3)) : w;
        bx = t / gridDim.y;
        by = t - bx * gridDim.y;
    }
    const long m0 = (long)by * 256;
    const long n0 = (long)bx * 128;

    const size_t KB = (size_t)KC << 10;
    const int8_t* ps  = Bsh + (size_t)((n0 >> 5) + wave) * KB + lane * 16;
    const int8_t* pa0 = Ash + (size_t)(((m0 + wm) >> 5) + 0) * KB + lane * 16;
    const int8_t* pa1 = Ash + (size_t)(((m0 + wm) >> 5) + 1) * KB + lane * 16;
    const int8_t* pa2 = Ash + (size_t)(((m0 + wm) >> 5) + 2) * KB + lane * 16;
    const int8_t* pa3 = Ash + (size_t)(((m0 + wm) >> 5) + 3) * KB + lane * 16;

    const int boff = (wave & 1) * 8192 + lane * 16;
    const int woff = wave * 4096 + lane * 16;

    i32x16 acc[4][2];
    #pragma unroll
    for (int i = 0; i < 4; ++i)
        #pragma unroll
        for (int j = 0; j < 2; ++j)
            acc[i][j] = i32x16{0,0,0,0,0,0,0,0,0,0,0,0,0,0,0,0};

#define SING_MFMA(B0, B1, A0, A1, A2, A3) do { \
    __builtin_amdgcn_s_setprio(1); \
    acc[0][0] = MFMA_I8(A0, B0, acc[0][0], 0, 0, 0); \
    acc[0][1] = MFMA_I8(A0, B1, acc[0][1], 0, 0, 0); \
    acc[1][0] = MFMA_I8(A1, B0, acc[1][0], 0, 0, 0); \
    acc[1][1] = MFMA_I8(A1, B1, acc[1][1], 0, 0, 0); \
    acc[2][0] = MFMA_I8(A2, B0, acc[2][0], 0, 0, 0); \
    acc[2][1] = MFMA_I8(A2, B1, acc[2][1], 0, 0, 0); \
    acc[3][0] = MFMA_I8(A3, B0, acc[3][0], 0, 0, 0); \
    acc[3][1] = MFMA_I8(A3, B1, acc[3][1], 0, 0, 0); \
    __builtin_amdgcn_s_setprio(0); } while (0)

    {
        i32x4 s0 = LDF(ps, 0), s1 = LDF(ps, 1024);
        i32x4 s2 = LDF(ps, 2048), s3 = LDF(ps, 3072);
        *(i32x4*)(Bsm + woff +    0) = s0;
        *(i32x4*)(Bsm + woff + 1024) = s1;
        *(i32x4*)(Bsm + woff + 2048) = s2;
        *(i32x4*)(Bsm + woff + 3072) = s3;
    }
    ps += 4096;
    i32x4 fa0 = LDF(pa0, 0),    fa1 = LDF(pa1, 0);
    i32x4 fa2 = LDF(pa2, 0),    fa3 = LDF(pa3, 0);
    i32x4 ha0 = LDF(pa0, 1024), ha1 = LDF(pa1, 1024);
    i32x4 ha2 = LDF(pa2, 1024), ha3 = LDF(pa3, 1024);
    LGKM0(); SCHEDB(); BAR();

    const int NT = KC >> 2;             // 44 tiles
    for (int kt = 0; kt < NT; ++kt) {
        const int8_t* cb = Bsm + (kt & 1) * 16384;
        int8_t* nb = Bsm + ((kt + 1) & 1) * 16384;
        const bool pf = (kt + 1) < NT;

        i32x4 st0, st1, st2, st3;
        if (pf) {
            st0 = LDF(ps, 0);    st1 = LDF(ps, 1024);
            st2 = LDF(ps, 2048); st3 = LDF(ps, 3072);
        }
        ps += 4096;

        i32x4 bA0 = *(const i32x4*)(cb + boff +    0);
        i32x4 bB0 = *(const i32x4*)(cb + boff + 4096);
        i32x4 bA1 = *(const i32x4*)(cb + boff + 1024);
        i32x4 bB1 = *(const i32x4*)(cb + boff + 5120);

        SING_MFMA(bA0, bB0, fa0, fa1, fa2, fa3);
        fa0 = LDF(pa0, 2048); fa1 = LDF(pa1, 2048);
        fa2 = LDF(pa2, 2048); fa3 = LDF(pa3, 2048);

        i32x4 bA2 = *(const i32x4*)(cb + boff + 2048);
        i32x4 bB2 = *(const i32x4*)(cb + boff + 6144);
        i32x4 bA3 = *(const i32x4*)(cb + boff + 3072);
        i32x4 bB3 = *(const i32x4*)(cb + boff + 7168);

        SING_MFMA(bA1, bB1, ha0, ha1, ha2, ha3);
        ha0 = LDF(pa0, 3072); ha1 = LDF(pa1, 3072);
        ha2 = LDF(pa2, 3072); ha3 = LDF(pa3, 3072);
        pa0 += 2048; pa1 += 2048; pa2 += 2048; pa3 += 2048;

        SING_MFMA(bA2, bB2, fa0, fa1, fa2, fa3);
        fa0 = LDF(pa0, 2048); fa1 = LDF(pa1, 2048);
        fa2 = LDF(pa2, 2048); fa3 = LDF(pa3, 2048);

        SING_MFMA(bA3, bB3, ha0, ha1, ha2, ha3);
        ha0 = LDF(pa0, 3072); ha1 = LDF(pa1, 3072);
        ha2 = LDF(pa2, 3072); ha3 = LDF(pa3, 3072);
        pa0 += 2048; pa1 += 2048; pa2 += 2048; pa3 += 2048;

        if (pf) {
            *(i32x4*)(nb + woff +    0) = st0;
            *(i32x4*)(nb + woff + 1024) = st1;
            *(i32x4*)(nb + woff + 2048) = st2;
            *(i32x4*)(nb + woff + 3072) = st3;
        }
        LGKM0(); SCHEDB(); BAR();
    }

    float sb[2];
    #pragma unroll
    for (int ni = 0; ni < 2; ++ni) sb[ni] = sB[n0 + wn + ni * 32 + cl];
    #pragma unroll
    for (int mi = 0; mi < 4; ++mi) {
        #pragma unroll
        for (int reg = 0; reg < 16; ++reg) {
            long m = m0 + wm + mi * 32 + (reg & 3) + 8 * (reg >> 2) + 4 * kq;
            float sa = sA[m];
            #pragma unroll
            for (int ni = 0; ni < 2; ++ni) {
                long n = n0 + wn + ni * 32 + cl;
                O[m * N + n] = (float)acc[mi][ni][reg] * sa * sb[ni];
            }
        }
    }
}

// ---------------------------------------------------------------------------

extern "C" void kernel_launch(void* const* d_in, const int* in_sizes, int n_in,
                              void* d_out, int out_size, void* d_ws, size_t ws_size,
                              hipStream_t stream)
{
    const float* x  = (const float*)d_in[0];   // [4,2048,2048]
    const float* Wg = (const float*)d_in[1];   // [5632,2048]
    const float* Wu = (const float*)d_in[2];   // [5632,2048]
    const float* Wd = (const float*)d_in[3];   // [2048,5632]
    float* out = (float*)d_out;                // [4,2048,2048] fp32

    const int M  = 8192;      // B*S
    const int H  = 2048;
    const int I  = 5632;

    // ---- fixed workspace regions (~49.1 MiB) ----
    char* p = (char*)d_ws;
    int8_t* xq  = (int8_t*)p; p += (size_t)M * H;
    float*  sx  = (float*)p;  p += (size_t)M * 4;
    int8_t* wgq = (int8_t*)p; p += (size_t)I * H;
    float*  swg = (float*)p;  p += (size_t)I * 4;
    int8_t* wuq = (int8_t*)p; p += (size_t)I * H;
    float*  swu = (float*)p;  p += (size_t)I * 4;
    int8_t* wdq = (int8_t*)p; p += (size_t)H * I;
    float*  swd = (float*)p;  p += (size_t)H * 4;
    float*  sh  = (float*)p;  p += (size_t)M * 4;
    const size_t fixed_bytes = (size_t)(p - (char*)d_ws);

    // ---- largest M-chunk whose h (fp32) + hq (int8) fit ws_size ----
    // (+8 KB slack: flat-stream rolling prefetch may over-read <=2 KB past hq)
    int Mc = 256;
    for (int cand = 8192; cand >= 256; cand >>= 1) {
        size_t need = fixed_bytes + (size_t)cand * I * 5 + 8192;
        if (need <= ws_size) { Mc = cand; break; }
    }
    float*  hbuf = (float*)p;  p += (size_t)Mc * I * 4;
    int8_t* hq   = (int8_t*)p;

    // 1) quantize weights (qmax=7) and activations (qmax=127) into flat layout
    quant_rows_shuf<<<I, 256, 0, stream>>>(Wg, wgq, swg, H / 4, 7.f);
    quant_rows_shuf<<<I, 256, 0, stream>>>(Wu, wuq, swu, H / 4, 7.f);
    quant_rows_shuf<<<H, 256, 0, stream>>>(Wd, wdq, swd, I / 4, 7.f);
    quant_rows_shuf<<<M, 256, 0, stream>>>(x,  xq,  sx,  H / 4, 127.f);

    // 2) per M-chunk: gate+up GEMM + SwiGLU -> h ; quantize h ; down-proj
    for (int m0 = 0; m0 < M; m0 += Mc) {
        gemm_dual_hyb<<<dim3(I / 128, Mc / 128), 256, 0, stream>>>(
            xq + (size_t)m0 * H, sx + m0, wgq, swg, wuq, swu,
            hbuf, Mc, I, H);
        quant_rows_shuf<<<Mc, 256, 0, stream>>>(hbuf, hq, sh + m0, I / 4, 127.f);
        gemm_single_hyb<<<dim3(H / 128, Mc / 256), 256, 0, stream>>>(
            hq, sh + m0, wdq, swd, out + (size_t)m0 * H, Mc, H, I);
    }
}